// Round 8
// baseline (1121.616 us; speedup 1.0000x reference)
//
#include <hip/hip_runtime.h>
#include <cstddef>
#include <cstdint>
#include <math.h>

#define Bsz   2
#define Sdim  2048
#define Hn    16
#define Ddim  1024
#define DEPTH 64
#define Mrows (Bsz * Sdim)
#define QTILES (Sdim / 64)
#define SZ    ((size_t)Bsz * Sdim * Ddim)   // 4,194,304 elements

typedef __attribute__((ext_vector_type(8))) short short8v;
typedef __attribute__((ext_vector_type(4))) float f32x4;

// ---------------------------------------------------------------------------
// fp32 -> packed (bf16 hi | bf16 lo) in one u32.
// hi = truncated top 16 bits (exact); lo = RNE-bf16 of the residual.
// hi+lo carries ~17 mantissa bits -> split-bf16 GEMM error ~1e-4 relative.
// ---------------------------------------------------------------------------
__device__ __forceinline__ uint32_t pack_hl(float x) {
    const uint32_t u  = __float_as_uint(x);
    const uint32_t hi = u & 0xFFFF0000u;
    const float    r  = x - __uint_as_float(hi);
    const uint32_t v  = __float_as_uint(r);
    const uint32_t lo = (v + 0x7FFFu + ((v >> 16) & 1u)) >> 16;
    return hi | lo;
}

// unpack 8 packed elems (2x uint4) into hi / lo bf16 fragments (short8).
// element order = load order; same slot->k bijection on A and B cancels.
__device__ __forceinline__ void unpack_frag(const uint4& r0, const uint4& r1,
                                            short8v& hi, short8v& lo)
{
    union { uint32_t u[4]; short8v v; } H, L;
    const uint32_t p[8] = {r0.x, r0.y, r0.z, r0.w, r1.x, r1.y, r1.z, r1.w};
#pragma unroll
    for (int q = 0; q < 4; ++q) {
        const uint32_t p0 = p[2 * q], p1 = p[2 * q + 1];
        H.u[q] = (p0 >> 16) | (p1 & 0xFFFF0000u);
        L.u[q] = (p0 & 0xFFFFu) | (p1 << 16);
    }
    hi = H.v; lo = L.v;
}

// ---------------------------------------------------------------------------
// Pack + transpose a 1024x1024 weight: Wt[n][k] = pack_hl(W[k][n]).
// ---------------------------------------------------------------------------
__device__ __forceinline__ void pack_w_body(const float* __restrict__ W,
                                            uint32_t* __restrict__ Wt)
{
    __shared__ uint32_t T[64][65];
    const int n0  = blockIdx.x * 64;
    const int k0  = blockIdx.y * 64;
    const int tid = threadIdx.x;
    const int c   = tid & 63;
    const int r0  = tid >> 6;
#pragma unroll
    for (int i = 0; i < 16; ++i) {
        const int kk = r0 * 16 + i;
        T[c][kk] = pack_hl(W[(size_t)(k0 + kk) * 1024 + n0 + c]);
    }
    __syncthreads();
#pragma unroll
    for (int i = 0; i < 16; ++i) {
        const int nn = r0 * 16 + i;
        Wt[(size_t)(n0 + nn) * 1024 + k0 + c] = T[nn][c];
    }
}

__global__ __launch_bounds__(256) void pack_w_kernel(const float* __restrict__ W,
                                                     uint32_t* __restrict__ Wt)
{
    pack_w_body(W, Wt);
}

__global__ __launch_bounds__(256) void pack_w3_kernel(
    const float* __restrict__ Wq, const float* __restrict__ Wk,
    const float* __restrict__ Wv,
    uint32_t* __restrict__ WtQ, uint32_t* __restrict__ WtK,
    uint32_t* __restrict__ WtV)
{
    const float* W; uint32_t* Wt;
    switch (blockIdx.z) {
        case 0:  W = Wq; Wt = WtQ; break;
        case 1:  W = Wk; Wt = WtK; break;
        default: W = Wv; Wt = WtV; break;
    }
    pack_w_body(W, Wt);
}

// ---------------------------------------------------------------------------
// pack_x: fp32 [4096][1024] -> packed u32, CHUNK-SWIZZLED for global_load_lds
// staging: within each 32-elem k-segment, 16B chunk c stored at c ^ (row&7).
// Read side XORs the same key -> LDS frag reads are bank-conflict-free.
// ---------------------------------------------------------------------------
__device__ __forceinline__ void pack_x_body(const float* __restrict__ X,
                                            uint32_t* __restrict__ Xp)
{
    const size_t t  = (size_t)blockIdx.x * 256 + threadIdx.x;  // one 4-elem chunk
    const size_t e0 = t * 4;
    const int m    = (int)(e0 >> 10);
    const int kin  = (int)(e0 & 1023);
    const int kseg = kin >> 5;
    const int ch   = (kin & 31) >> 2;
    const float4 x = *reinterpret_cast<const float4*>(&X[e0]);
    uint4 o;
    o.x = pack_hl(x.x); o.y = pack_hl(x.y); o.z = pack_hl(x.z); o.w = pack_hl(x.w);
    const int chp = ch ^ (m & 7);
    *reinterpret_cast<uint4*>(
        &Xp[((size_t)m << 10) + (kseg << 5) + (chp << 2)]) = o;
}

__global__ __launch_bounds__(256) void pack_x_kernel(const float* __restrict__ X,
                                                     uint32_t* __restrict__ Xp)
{
    pack_x_body(X, Xp);
}

__global__ __launch_bounds__(256) void pack_x3_kernel(
    const float* __restrict__ q, const float* __restrict__ k,
    const float* __restrict__ v,
    uint32_t* __restrict__ XpQ, uint32_t* __restrict__ XpK,
    uint32_t* __restrict__ XpV)
{
    const float* X; uint32_t* Xp;
    switch (blockIdx.z) {
        case 0:  X = q; Xp = XpQ; break;
        case 1:  X = k; Xp = XpK; break;
        default: X = v; Xp = XpV; break;
    }
    pack_x_body(X, Xp);
}

// ---------------------------------------------------------------------------
// zero-fill (restores zeros in the scribbled attn-output scratch region)
// ---------------------------------------------------------------------------
__global__ __launch_bounds__(256) void zero_kernel(float4* __restrict__ p)
{
    const size_t i = (size_t)blockIdx.x * 256 + threadIdx.x;
    p[i] = make_float4(0.f, 0.f, 0.f, 0.f);
}

// ---------------------------------------------------------------------------
// Split-bf16 MFMA GEMM, m97-style staging: A pre-packed+swizzled in global,
// staged to LINEAR LDS via global_load_lds (16B), frag reads XOR-deswizzle.
// B (Wt[n][k] packed) direct from L2 per fragment. 128x128 tile, BK=32.
// ---------------------------------------------------------------------------
template <bool SPLIT, bool PACK>
__device__ __forceinline__ void mfma_gemm(const uint32_t* __restrict__ Xp,
                                          const uint32_t* __restrict__ Wt,
                                          const float* __restrict__ bias,
                                          void* __restrict__ Yv,
                                          float oscale)
{
    constexpr int K = 1024;
    __shared__ __align__(16) uint32_t Apk[128 * 32];  // linear, swizzled content

    const int tid  = threadIdx.x;
    const int lane = tid & 63;
    const int wid  = tid >> 6;
    const int wr   = wid >> 1;
    const int wc   = wid & 1;
    const int l15  = lane & 15;
    const int lg   = lane >> 4;

    const int m0 = blockIdx.y * 128;
    const int n0 = blockIdx.x * 128;

    // staging: wave wid, instr i covers rows wid*32 + i*8 + (lane>>3), chunk lane&7
    const int ldrow = wid * 32 + (lane >> 3);
    const int ldj   = lane & 7;
    const uint32_t* gsrc = Xp + (size_t)(m0 + ldrow) * K + ldj * 4;

    const uint32_t* wp[4];
#pragma unroll
    for (int fj = 0; fj < 4; ++fj)
        wp[fj] = Wt + (size_t)(n0 + wc * 64 + fj * 16 + l15) * K + lg * 8;

    f32x4 acc[4][4] = {};
    const int rk = l15 & 7;   // read-side swizzle key

    for (int k0 = 0; k0 < K; k0 += 32) {
        // B fragments (global, L2-hot, no LDS dependency) — issue first
        uint4 braw[4][2];
#pragma unroll
        for (int fj = 0; fj < 4; ++fj) {
            braw[fj][0] = *reinterpret_cast<const uint4*>(wp[fj] + k0);
            braw[fj][1] = *reinterpret_cast<const uint4*>(wp[fj] + k0 + 4);
        }

        // A tile: async global->LDS (wave-uniform LDS base + lane*16)
#pragma unroll
        for (int i = 0; i < 4; ++i) {
            __builtin_amdgcn_global_load_lds(
                (const __attribute__((address_space(1))) uint32_t*)(
                    gsrc + (size_t)i * 8 * K + k0),
                (__attribute__((address_space(3))) uint32_t*)(
                    &Apk[(wid * 32 + i * 8) * 32]),
                16, 0, 0);
        }
        __syncthreads();

        short8v bhi[4], blo[4];
#pragma unroll
        for (int fj = 0; fj < 4; ++fj)
            unpack_frag(braw[fj][0], braw[fj][1], bhi[fj], blo[fj]);

#pragma unroll
        for (int fi = 0; fi < 4; ++fi) {
            const int row = wr * 64 + fi * 16 + l15;
            const int j0  = (2 * lg) ^ rk;
            const int j1  = j0 ^ 1;
            const uint4 a0 = *reinterpret_cast<const uint4*>(&Apk[row * 32 + j0 * 4]);
            const uint4 a1 = *reinterpret_cast<const uint4*>(&Apk[row * 32 + j1 * 4]);
            short8v ahi, alo;
            unpack_frag(a0, a1, ahi, alo);
#pragma unroll
            for (int fj = 0; fj < 4; ++fj) {
                acc[fi][fj] = __builtin_amdgcn_mfma_f32_16x16x32_bf16(
                    ahi, bhi[fj], acc[fi][fj], 0, 0, 0);
                acc[fi][fj] = __builtin_amdgcn_mfma_f32_16x16x32_bf16(
                    ahi, blo[fj], acc[fi][fj], 0, 0, 0);
                acc[fi][fj] = __builtin_amdgcn_mfma_f32_16x16x32_bf16(
                    alo, bhi[fj], acc[fi][fj], 0, 0, 0);
            }
        }
        __syncthreads();
    }

#pragma unroll
    for (int fj = 0; fj < 4; ++fj) {
        const int col = n0 + wc * 64 + fj * 16 + l15;
        const float bv = bias[col];
#pragma unroll
        for (int fi = 0; fi < 4; ++fi) {
#pragma unroll
            for (int j = 0; j < 4; ++j) {
                const int row = m0 + wr * 64 + fi * 16 + lg * 4 + j;
                const float val = (acc[fi][fj][j] + bv) * oscale;
                size_t idx;
                if (SPLIT) {
                    const int bb = row >> 11;
                    const int ss = row & 2047;
                    const int hh = col >> 6;
                    const int dd = col & 63;
                    idx = (((size_t)bb * Hn + hh) * Sdim + ss) * DEPTH + dd;
                } else {
                    idx = (size_t)row * Ddim + col;
                }
                if (PACK) ((uint32_t*)Yv)[idx] = pack_hl(val);
                else      ((float*)Yv)[idx]    = val;
            }
        }
    }
}

__global__ __launch_bounds__(256) void proj_kernel(
    const uint32_t* __restrict__ XpQ, const uint32_t* __restrict__ XpK,
    const uint32_t* __restrict__ XpV,
    const uint32_t* __restrict__ WtQ, const uint32_t* __restrict__ WtK,
    const uint32_t* __restrict__ WtV,
    const float* __restrict__ bq, const float* __restrict__ bk,
    const float* __restrict__ bv,
    uint32_t* __restrict__ qh, uint32_t* __restrict__ kh,
    uint32_t* __restrict__ vh)
{
    const uint32_t* X; const uint32_t* W; const float* bias; uint32_t* Y;
    float sc = 1.0f;
    switch (blockIdx.z) {
        case 0:  X = XpQ; W = WtQ; bias = bq; Y = qh; sc = 0.125f; break;
        case 1:  X = XpK; W = WtK; bias = bk; Y = kh; break;
        default: X = XpV; W = WtV; bias = bv; Y = vh; break;
    }
    mfma_gemm<true, true>(X, W, bias, Y, sc);
}

__global__ __launch_bounds__(256) void oproj_kernel(
    const uint32_t* __restrict__ ctxp, const uint32_t* __restrict__ WtO,
    const float* __restrict__ bo, float* __restrict__ out)
{
    mfma_gemm<false, false>(ctxp, WtO, bo, out, 1.0f);
}

// ---------------------------------------------------------------------------
// MFMA attention, BOTH passes swapped: mfma(K, Q) -> S^T (lane: col=q=l15,
// rows k=fc*16+lg*4+j). Softmax is in-lane + 2 shuffles; stats stay in
// registers for pass 2 (same lane layout). Pass 2 keeps P IN REGISTERS as
// the PV A-fragment via a custom slot->k bijection ({lg*4+t} then
// {16+lg*4+t}) applied identically to the V-fragment (two uint4 reads from
// Vt) -> no P LDS round-trip, no stats exchange, ONE barrier per tile
// (double-buffered Vt). attn stores are float4. PV output layout lands on
// the ctx concat write directly.
// ---------------------------------------------------------------------------
__global__ __launch_bounds__(256) void attn_mfma_kernel(
    const uint32_t* __restrict__ qpk, const uint32_t* __restrict__ kpk,
    const uint32_t* __restrict__ vpk,
    float* __restrict__ attn, float* __restrict__ ctx)
{
    __shared__ __align__(16) uint32_t Vt[2][64][68];  // V^T dbuf: [d][key]

    // block mapping: xcd = n&7 keeps all q-tiles of a (b,h) on one XCD
    const int n   = blockIdx.x;
    const int xcd = n & 7;
    const int s   = n >> 3;
    const int c   = ((s >> 5) << 3) | xcd;    // (b,h) combo 0..31
    const int qt  = 31 - (s & 31);            // heavy tiles first
    const int b   = c >> 4;
    const int h   = c & 15;

    const int tid  = threadIdx.x;
    const int lane = tid & 63;
    const int wid  = tid >> 6;
    const int l15  = lane & 15;
    const int lg   = lane >> 4;

    const size_t head = ((size_t)(b * Hn + h)) * Sdim * DEPTH;
    const int q0 = qt * 64;

    const uint32_t* kh_head = kpk + head;
    const uint32_t* vh_head = vpk + head;

    // ---- Q fragments (pre-scaled by 1/8) hoisted; B-operand layout ----
    short8v qhi[2], qlo[2];
    {
        const uint32_t* qp = qpk + head +
            (size_t)(q0 + wid * 16 + l15) * DEPTH + lg * 8;
#pragma unroll
        for (int kk = 0; kk < 2; ++kk) {
            const uint4 r0 = *reinterpret_cast<const uint4*>(qp + kk * 32);
            const uint4 r1 = *reinterpret_cast<const uint4*>(qp + kk * 32 + 4);
            unpack_frag(r0, r1, qhi[kk], qlo[kk]);
        }
    }

    // lane state: (m,s) for q = q0 + wid*16 + l15 (replicated across lg)
    float m_s = -INFINITY, s_s = 0.f;
    const int qg_l = q0 + wid * 16 + l15;

    // ---------------- pass 1: stats (no LDS, no barriers) ----------------
    for (int kt = 0; kt <= qt; ++kt) {
        const int k0 = kt * 64;
        f32x4 sacc[4] = {};
#pragma unroll
        for (int fc = 0; fc < 4; ++fc) {
            const uint32_t* p =
                kh_head + (size_t)(k0 + fc * 16 + l15) * DEPTH + lg * 8;
            const uint4 r00 = *reinterpret_cast<const uint4*>(p);
            const uint4 r01 = *reinterpret_cast<const uint4*>(p + 4);
            const uint4 r10 = *reinterpret_cast<const uint4*>(p + 32);
            const uint4 r11 = *reinterpret_cast<const uint4*>(p + 36);
            short8v khi, klo;
            unpack_frag(r00, r01, khi, klo);
            sacc[fc] = __builtin_amdgcn_mfma_f32_16x16x32_bf16(khi, qhi[0], sacc[fc], 0, 0, 0);
            sacc[fc] = __builtin_amdgcn_mfma_f32_16x16x32_bf16(khi, qlo[0], sacc[fc], 0, 0, 0);
            sacc[fc] = __builtin_amdgcn_mfma_f32_16x16x32_bf16(klo, qhi[0], sacc[fc], 0, 0, 0);
            unpack_frag(r10, r11, khi, klo);
            sacc[fc] = __builtin_amdgcn_mfma_f32_16x16x32_bf16(khi, qhi[1], sacc[fc], 0, 0, 0);
            sacc[fc] = __builtin_amdgcn_mfma_f32_16x16x32_bf16(khi, qlo[1], sacc[fc], 0, 0, 0);
            sacc[fc] = __builtin_amdgcn_mfma_f32_16x16x32_bf16(klo, qhi[1], sacc[fc], 0, 0, 0);
        }

        if (kt == qt) {
#pragma unroll
            for (int fc = 0; fc < 4; ++fc)
#pragma unroll
                for (int j = 0; j < 4; ++j)
                    if (k0 + fc * 16 + lg * 4 + j > qg_l)
                        sacc[fc][j] = -INFINITY;
        }

        float tmax = -INFINITY;
#pragma unroll
        for (int fc = 0; fc < 4; ++fc)
#pragma unroll
            for (int j = 0; j < 4; ++j) tmax = fmaxf(tmax, sacc[fc][j]);
        tmax = fmaxf(tmax, __shfl_xor(tmax, 16, 64));
        tmax = fmaxf(tmax, __shfl_xor(tmax, 32, 64));

        const float mnew = fmaxf(m_s, tmax);
        float ps = 0.f;
#pragma unroll
        for (int fc = 0; fc < 4; ++fc)
#pragma unroll
            for (int j = 0; j < 4; ++j) ps += __expf(sacc[fc][j] - mnew);
        ps += __shfl_xor(ps, 16, 64);
        ps += __shfl_xor(ps, 32, 64);

        s_s = s_s * __expf(m_s - mnew) + ps;
        m_s = mnew;
    }

    const float inv_ss = 1.f / s_s;

    f32x4 cacc[4] = {};   // ctx acc: [d-frag], D rows = q = lg*4+j

    const int vr = tid >> 2;        // V staging: key row 0..63
    const int vq = tid & 3;

    // ---------------- pass 2: swapped QK^T, in-register P, PV ------------
    for (int kt = 0; kt <= qt; ++kt) {
        const int k0 = kt * 64;

        // V staging loads (coalesced 64B rows) — issue before compute
        uint4 vraw[4];
#pragma unroll
        for (int i = 0; i < 4; ++i)
            vraw[i] = *reinterpret_cast<const uint4*>(
                vh_head + (size_t)(k0 + vr) * DEPTH + (vq + 4 * i) * 4);

        // swapped QK^T (same as pass 1)
        f32x4 sacc[4] = {};
#pragma unroll
        for (int fc = 0; fc < 4; ++fc) {
            const uint32_t* p =
                kh_head + (size_t)(k0 + fc * 16 + l15) * DEPTH + lg * 8;
            const uint4 r00 = *reinterpret_cast<const uint4*>(p);
            const uint4 r01 = *reinterpret_cast<const uint4*>(p + 4);
            const uint4 r10 = *reinterpret_cast<const uint4*>(p + 32);
            const uint4 r11 = *reinterpret_cast<const uint4*>(p + 36);
            short8v khi, klo;
            unpack_frag(r00, r01, khi, klo);
            sacc[fc] = __builtin_amdgcn_mfma_f32_16x16x32_bf16(khi, qhi[0], sacc[fc], 0, 0, 0);
            sacc[fc] = __builtin_amdgcn_mfma_f32_16x16x32_bf16(khi, qlo[0], sacc[fc], 0, 0, 0);
            sacc[fc] = __builtin_amdgcn_mfma_f32_16x16x32_bf16(klo, qhi[0], sacc[fc], 0, 0, 0);
            unpack_frag(r10, r11, khi, klo);
            sacc[fc] = __builtin_amdgcn_mfma_f32_16x16x32_bf16(khi, qhi[1], sacc[fc], 0, 0, 0);
            sacc[fc] = __builtin_amdgcn_mfma_f32_16x16x32_bf16(khi, qlo[1], sacc[fc], 0, 0, 0);
            sacc[fc] = __builtin_amdgcn_mfma_f32_16x16x32_bf16(klo, qhi[1], sacc[fc], 0, 0, 0);
        }

        // p = exp(S - m)/s, mask, attn float4 stores, build P fragments
        const bool diag = (kt == qt);
        float pv[4][4];
        float* arow = attn + ((size_t)(b * Hn + h) * Sdim + qg_l) * Sdim + k0;
#pragma unroll
        for (int fc = 0; fc < 4; ++fc) {
#pragma unroll
            for (int j = 0; j < 4; ++j) {
                const int kk = k0 + fc * 16 + lg * 4 + j;
                float p = __expf(sacc[fc][j] - m_s) * inv_ss;
                if (diag && kk > qg_l) p = 0.f;
                pv[fc][j] = p;
            }
            *reinterpret_cast<float4*>(arow + fc * 16 + lg * 4) =
                make_float4(pv[fc][0], pv[fc][1], pv[fc][2], pv[fc][3]);
        }

        short8v phi[2], plo[2];
#pragma unroll
        for (int c2 = 0; c2 < 2; ++c2) {
#pragma unroll
            for (int j = 0; j < 4; ++j) {
                const uint32_t u0 = pack_hl(pv[2 * c2][j]);
                const uint32_t u1 = pack_hl(pv[2 * c2 + 1][j]);
                phi[c2][j]     = (short)(u0 >> 16);
                plo[c2][j]     = (short)(u0 & 0xFFFFu);
                phi[c2][4 + j] = (short)(u1 >> 16);
                plo[c2][4 + j] = (short)(u1 & 0xFFFFu);
            }
        }

        // stage V transposed into this tile's buffer, ONE barrier
        uint32_t (*Vtb)[68] = Vt[kt & 1];
#pragma unroll
        for (int i = 0; i < 4; ++i) {
            const int c0 = (vq + 4 * i) * 4;
            Vtb[c0 + 0][vr] = vraw[i].x;
            Vtb[c0 + 1][vr] = vraw[i].y;
            Vtb[c0 + 2][vr] = vraw[i].z;
            Vtb[c0 + 3][vr] = vraw[i].w;
        }
        __syncthreads();

        // PV: ctx += P @ V. A = in-register P; B = V frags with the SAME
        // slot->k map: slots 0..3 -> k=c2*32+lg*4+t, slots 4..7 -> +16.
#pragma unroll
        for (int c2 = 0; c2 < 2; ++c2) {
#pragma unroll
            for (int fd = 0; fd < 4; ++fd) {
                const uint32_t* bp = &Vtb[fd * 16 + l15][c2 * 32 + lg * 4];
                const uint4 b0 = *reinterpret_cast<const uint4*>(bp);
                const uint4 b1 = *reinterpret_cast<const uint4*>(bp + 16);
                short8v vhi, vlo;
                unpack_frag(b0, b1, vhi, vlo);
                cacc[fd] = __builtin_amdgcn_mfma_f32_16x16x32_bf16(phi[c2], vhi, cacc[fd], 0, 0, 0);
                cacc[fd] = __builtin_amdgcn_mfma_f32_16x16x32_bf16(phi[c2], vlo, cacc[fd], 0, 0, 0);
                cacc[fd] = __builtin_amdgcn_mfma_f32_16x16x32_bf16(plo[c2], vhi, cacc[fd], 0, 0, 0);
            }
        }
    }

    // ctx in concat layout (B, S, D): D rows = q = lg*4+j, cols = d = l15
#pragma unroll
    for (int fd = 0; fd < 4; ++fd)
#pragma unroll
        for (int j = 0; j < 4; ++j) {
            const int qg = q0 + wid * 16 + lg * 4 + j;
            ctx[((size_t)b * Sdim + qg) * Ddim + h * DEPTH + fd * 16 + l15] =
                cacc[fd][j];
        }
}

// ---------------------------------------------------------------------------
extern "C" void kernel_launch(void* const* d_in, const int* in_sizes, int n_in,
                              void* d_out, int out_size, void* d_ws, size_t ws_size,
                              hipStream_t stream)
{
    (void)in_sizes; (void)n_in; (void)out_size; (void)ws_size;

    const float* v  = (const float*)d_in[0];
    const float* k  = (const float*)d_in[1];
    const float* q  = (const float*)d_in[2];
    const float* Wq = (const float*)d_in[4];
    const float* bq = (const float*)d_in[5];
    const float* Wk = (const float*)d_in[6];
    const float* bk = (const float*)d_in[7];
    const float* Wv = (const float*)d_in[8];
    const float* bv = (const float*)d_in[9];
    const float* Wo = (const float*)d_in[10];
    const float* bo = (const float*)d_in[11];

    float* out  = (float*)d_out;
    float* attn = out + SZ;

    float* ws  = (float*)d_ws;
    uint32_t* qh = (uint32_t*)ws;            // packed hi|lo (head-split)
    uint32_t* kh = qh + SZ;
    uint32_t* vh = kh + SZ;
    float*   ctx = (float*)(vh + SZ);

    // ws aliasing (stream-ordered): WtQ/K/V live in ctx region (consumed by
    // proj before attn writes ctx). After attn: ctxp aliases qh, WtO aliases kh.
    uint32_t* WtQ  = (uint32_t*)ctx;
    uint32_t* WtK  = WtQ + 1024 * 1024;
    uint32_t* WtV  = WtK + 1024 * 1024;
    uint32_t* ctxp = qh;
    uint32_t* WtO  = kh;

    // Xp scratch scribbles the not-yet-written attn output region (48 MB),
    // zero-restored before attn runs (r4-validated pattern).
    uint32_t* XpQ = (uint32_t*)attn;
    uint32_t* XpK = XpQ + SZ;
    uint32_t* XpV = XpK + SZ;

    dim3 gpk3(16, 16, 3);
    pack_w3_kernel<<<gpk3, 256, 0, stream>>>(Wq, Wk, Wv, WtQ, WtK, WtV);

    pack_x3_kernel<<<dim3(4096, 1, 3), 256, 0, stream>>>(q, k, v, XpQ, XpK, XpV);

    dim3 gproj(Ddim / 128, Mrows / 128, 3);
    proj_kernel<<<gproj, 256, 0, stream>>>(XpQ, XpK, XpV, WtQ, WtK, WtV,
                                           bq, bk, bv, qh, kh, vh);

    zero_kernel<<<12288, 256, 0, stream>>>((float4*)attn);

    attn_mfma_kernel<<<dim3(QTILES * Hn * Bsz), 256, 0, stream>>>(
        qh, kh, vh, attn, ctx);

    dim3 gpk(16, 16);
    pack_w_kernel<<<gpk, 256, 0, stream>>>(Wo, WtO);
    pack_x_kernel<<<4096, 256, 0, stream>>>(ctx, ctxp);

    dim3 gout(Ddim / 128, Mrows / 128);
    oproj_kernel<<<gout, 256, 0, stream>>>(ctxp, WtO, bo, out);
}